// Round 6
// baseline (290.129 us; speedup 1.0000x reference)
//
#include <hip/hip_runtime.h>
#include <math.h>

// Sizes
#define NB 32
#define NL 512

// ws layout (floats):
// [0, 16384)            x_avg[b][l]
// [16384, 32768)        x_max[b][l]
// [32768, 32768+131072) ypart[c*2+half][b][l]   (8 slots of 16384)

__global__ __launch_bounds__(256) void kreduce(const float* __restrict__ in,
                                               float* __restrict__ xavg,
                                               float* __restrict__ xmax) {
    const int bl = blockIdx.x;            // 0..16383  (= b*512 + l)
    const float* p = in + (size_t)bl * 4096;
    const int t = threadIdx.x;
    float s = 0.f, m = -INFINITY;
#pragma unroll
    for (int it = 0; it < 4; ++it) {
        float4 v = *reinterpret_cast<const float4*>(p + (size_t)(it * 256 + t) * 4);
        s += v.x + v.y + v.z + v.w;
        m = fmaxf(m, fmaxf(fmaxf(v.x, v.y), fmaxf(v.z, v.w)));
    }
#pragma unroll
    for (int o = 1; o < 64; o <<= 1) {
        s += __shfl_xor(s, o);
        m = fmaxf(m, __shfl_xor(m, o));
    }
    __shared__ float ls[4], lm[4];
    const int w = t >> 6;
    if ((t & 63) == 0) { ls[w] = s; lm[w] = m; }
    __syncthreads();
    if (t == 0) {
        s = ls[0] + ls[1] + ls[2] + ls[3];
        m = fmaxf(fmaxf(lm[0], lm[1]), fmaxf(lm[2], lm[3]));
        xavg[bl] = s * (1.f / 4096.f);
        xmax[bl] = m;
    }
}

// DPP add over 16-lane rows: after shl 1,2,4,8, lane (s==0) of each row holds the row sum.
// (verified empirically: rounds 4/5 passed with absmax 0.0 using this chain)
#define DPP_ADD(v, ctrl) ((v) + __int_as_float(__builtin_amdgcn_update_dpp(0, __float_as_int(v), (ctrl), 0xF, 0xF, true)))

// One block per (call c in 0..3, d-half, batch b). 512 threads.
// Grid = 256 blocks = 1 block/CU, so we want the register allocator to budget
// for exactly 2 waves/EU (256 VGPR) — NOT the 4-waves/EU (128 VGPR + spill)
// the LDS-based occupancy heuristic picked in round 5 (427 MB scratch writes).
__global__ __launch_bounds__(512) __attribute__((amdgpu_waves_per_eu(2, 2))) void kmamba(
    const float* __restrict__ xavg, const float* __restrict__ xmax,
    float* __restrict__ ypart,
    const float* __restrict__ paw, const float* __restrict__ pab,
    const float* __restrict__ pmw, const float* __restrict__ pmb,
    const float* __restrict__ outw_outer,
    const float* __restrict__ f_in_w, const float* __restrict__ f_conv_w, const float* __restrict__ f_conv_b,
    const float* __restrict__ f_xproj_w, const float* __restrict__ f_dt_w, const float* __restrict__ f_dt_b,
    const float* __restrict__ f_A_log, const float* __restrict__ f_D, const float* __restrict__ f_out_w,
    const float* __restrict__ b_in_w, const float* __restrict__ b_conv_w, const float* __restrict__ b_conv_b,
    const float* __restrict__ b_xproj_w, const float* __restrict__ b_dt_w, const float* __restrict__ b_dt_b,
    const float* __restrict__ b_A_log, const float* __restrict__ b_D, const float* __restrict__ b_out_w)
{
    const int tid = threadIdx.x;
    const int c = blockIdx.x >> 6;
    const int half = (blockIdx.x >> 5) & 1;
    const int b = blockIdx.x & 31;
    const int strm = c >> 1, dir = c & 1;

    const float* in_w = dir ? b_in_w   : f_in_w;
    const float* cwp  = dir ? b_conv_w : f_conv_w;
    const float* cbp  = dir ? b_conv_b : f_conv_b;
    const float* xpw  = dir ? b_xproj_w: f_xproj_w;
    const float* dtwp = dir ? b_dt_w   : f_dt_w;
    const float* dtbp = dir ? b_dt_b   : f_dt_b;
    const float* alog = dir ? b_A_log  : f_A_log;
    const float* Dpar = dir ? b_D      : f_D;
    const float* owp  = dir ? b_out_w  : f_out_w;
    const float* projw = strm ? pmw : paw;
    const float* projb = strm ? pmb : pab;
    const float* xin   = strm ? xmax : xavg;

    __shared__ float sseq[512];
    __shared__ float su[128], sv[128];
    __shared__ float swf[64];
    __shared__ float scw[64][4], scb[64], sdtw[64][2], sdtb[64], sD[64];
    __shared__ float sxp[34][68];     // staged xproj_w rows (dt0,dt1,B0..15,C0..15)
    __shared__ float sxi[64][68];     // xi for all 64 d, current chunk (row-major)
    __shared__ float sdtv[64][4];     // dt0,dt1 per row
    __shared__ float sbcT[32][68];    // B(0..15),C(16..31) transposed: [j][row]
    __shared__ float sdeltaT[32][68]; // own-half delta, transposed [dd][row]
    __shared__ float sdxvT[32][68];   // own-half delta*xi, transposed
    __shared__ float sgdT[32][68];    // own-half silu(z)*wfold, transposed
    __shared__ float syT[32][68];     // per-d scan output, transposed
    __shared__ float sybase[64];      // per-row Sum_d gd*D*xi (own half)
    __shared__ float spad[1200];      // LDS pad: push block >80 KiB so the
                                      // occupancy heuristic can only see 1 block/CU

    // keep spad live without runtime effect (condition depends on input data,
    // never true for this problem's magnitudes)
    spad[tid] = 0.f;
    spad[512 + (tid & 511)] = 0.f;

    // one-time setup
    {
        int i = tid;
        int l = dir ? (511 - i) : i;
        sseq[i] = xin[b * 512 + l];
    }
    if (tid < 128) {
        float u = 0.f, v = 0.f;
        const float* row = in_w + tid * 32;
#pragma unroll
        for (int m = 0; m < 32; ++m) {
            u = fmaf(row[m], projw[m], u);
            v = fmaf(row[m], projb[m], v);
        }
        su[tid] = u; sv[tid] = v;
    }
    if (tid < 64) {
        int d = tid;
#pragma unroll
        for (int k = 0; k < 4; ++k) scw[d][k] = cwp[d * 4 + k];
        scb[d] = cbp[d];
        sdtw[d][0] = dtwp[d * 2];
        sdtw[d][1] = dtwp[d * 2 + 1];
        sdtb[d] = dtbp[d];
        sD[d] = Dpar[d];
        float wf = 0.f;
#pragma unroll
        for (int m = 0; m < 32; ++m) wf = fmaf(outw_outer[m], owp[m * 64 + d], wf);
        swf[d] = wf;
    }
    for (int i = tid; i < 34 * 64; i += 512) sxp[i >> 6][i & 63] = xpw[i];

    const int dd = tid >> 4;        // 0..31 (own-half local d)
    const int s  = tid & 15;        // state index
    const int d  = half * 32 + dd;  // global d
    const float cA = -expf(alog[d * 16 + s]) * 1.44269504088896340736f;
    float h = 0.f;                  // carried across all 8 chunks in-register

    const int ll8 = tid >> 3;       // 0..63 (phase-A row)
    const int j8  = tid & 7;

    __syncthreads();

    for (int chunk = 0; chunk < 8; ++chunk) {
        const int ibase = chunk * 64;

        // ---- A1: xi (post-conv, silu) for all 64 d ----
        {
            int i = ibase + ll8;
            float t0 = (i - 3 >= 0) ? sseq[i - 3] : 0.f;
            float t1 = (i - 2 >= 0) ? sseq[i - 2] : 0.f;
            float t2 = (i - 1 >= 0) ? sseq[i - 1] : 0.f;
            float t3 = sseq[i];
            float vv0 = (i - 3 >= 0) ? 1.f : 0.f;
            float vv1 = (i - 2 >= 0) ? 1.f : 0.f;
            float vv2 = (i - 1 >= 0) ? 1.f : 0.f;
#pragma unroll
            for (int k = 0; k < 8; ++k) {
                int di = j8 * 8 + k;
                float u = su[di], v = sv[di];
                float xc = scw[di][0] * fmaf(t0, u, vv0 * v)
                         + scw[di][1] * fmaf(t1, u, vv1 * v)
                         + scw[di][2] * fmaf(t2, u, vv2 * v)
                         + scw[di][3] * fmaf(t3, u, v);
                xc += scb[di];
                float sig = 1.f / (1.f + __expf(-xc));
                sxi[ll8][di] = xc * sig;
            }
        }
        __syncthreads();

        // ---- A2: dbc = xi @ xproj_w.T (34 outputs; w from LDS) ----
        {
            float a0 = 0.f, a1 = 0.f, a2 = 0.f, a3 = 0.f, a4 = 0.f;
            const float4* xr4 = reinterpret_cast<const float4*>(&sxi[ll8][0]);
            const float4* r0 = reinterpret_cast<const float4*>(&sxp[j8 + 0][0]);
            const float4* r1 = reinterpret_cast<const float4*>(&sxp[j8 + 8][0]);
            const float4* r2 = reinterpret_cast<const float4*>(&sxp[j8 + 16][0]);
            const float4* r3 = reinterpret_cast<const float4*>(&sxp[j8 + 24][0]);
            const float4* r4 = (j8 < 2) ? reinterpret_cast<const float4*>(&sxp[j8 + 32][0]) : r0;
            bool extra = (j8 < 2);
#pragma unroll
            for (int q = 0; q < 16; ++q) {
                float4 x = xr4[q];
                float4 w;
                w = r0[q]; a0 = fmaf(x.x,w.x,fmaf(x.y,w.y,fmaf(x.z,w.z,fmaf(x.w,w.w,a0))));
                w = r1[q]; a1 = fmaf(x.x,w.x,fmaf(x.y,w.y,fmaf(x.z,w.z,fmaf(x.w,w.w,a1))));
                w = r2[q]; a2 = fmaf(x.x,w.x,fmaf(x.y,w.y,fmaf(x.z,w.z,fmaf(x.w,w.w,a2))));
                w = r3[q]; a3 = fmaf(x.x,w.x,fmaf(x.y,w.y,fmaf(x.z,w.z,fmaf(x.w,w.w,a3))));
                if (extra) { w = r4[q]; a4 = fmaf(x.x,w.x,fmaf(x.y,w.y,fmaf(x.z,w.z,fmaf(x.w,w.w,a4)))); }
            }
            // j = j8: 0,1 -> dt; 2..33 -> B/C transposed
            if (j8 < 2) sdtv[ll8][j8] = a0; else sbcT[j8 - 2][ll8] = a0;
            sbcT[j8 + 6][ll8]  = a1;
            sbcT[j8 + 14][ll8] = a2;
            sbcT[j8 + 22][ll8] = a3;
            if (extra) sbcT[j8 + 30][ll8] = a4;
        }
        __syncthreads();

        // ---- A3: delta, delta*xi, gate*wfold (own half, transposed); ybase ----
        {
            float dt0 = sdtv[ll8][0], dt1 = sdtv[ll8][1];
            float xl = sseq[ibase + ll8];
            float ybp = 0.f;
            bool own = ((j8 >> 2) == half);
#pragma unroll
            for (int k = 0; k < 8; ++k) {
                int di = j8 * 8 + k;
                float pre = fmaf(dt0, sdtw[di][0], fmaf(dt1, sdtw[di][1], sdtb[di]));
                float sp = (pre > 20.f) ? pre : log1pf(__expf(pre));
                if (own) {
                    int ddx = (j8 & 3) * 8 + k;
                    float xiv = sxi[ll8][di];
                    sdeltaT[ddx][ll8] = sp;
                    sdxvT[ddx][ll8] = sp * xiv;
                    float zv = fmaf(xl, su[64 + di], sv[64 + di]);
                    float sig = 1.f / (1.f + __expf(-zv));
                    float gd = (zv * sig) * swf[di];
                    sgdT[ddx][ll8] = gd;
                    ybp = fmaf(gd * sD[di], xiv, ybp);
                }
            }
            ybp += __shfl_xor(ybp, 1);
            ybp += __shfl_xor(ybp, 2);
            ybp += __shfl_xor(ybp, 4);
            if (j8 == 0) sybase[ll8] = ybp;
        }
        __syncthreads();

        // ---- B: scan 64 steps, h carried in-register across chunks ----
        {
            const float4* dT = reinterpret_cast<const float4*>(&sdeltaT[dd][0]);
            const float4* xT = reinterpret_cast<const float4*>(&sdxvT[dd][0]);
            const float4* bT = reinterpret_cast<const float4*>(&sbcT[s][0]);
            const float4* cT = reinterpret_cast<const float4*>(&sbcT[16 + s][0]);
            const float4* gT = reinterpret_cast<const float4*>(&sgdT[dd][0]);
#pragma unroll 2
            for (int m = 0; m < 16; ++m) {
                float4 de = dT[m], dx = xT[m], Bq = bT[m], Cq = cT[m], gq = gT[m];
                float4 val;
                float a, pc;
                a = exp2f(de.x * cA); h = fmaf(a, h, dx.x * Bq.x); pc = h * Cq.x;
                pc = DPP_ADD(pc, 0x101); pc = DPP_ADD(pc, 0x102);
                pc = DPP_ADD(pc, 0x104); pc = DPP_ADD(pc, 0x108);
                val.x = pc * gq.x;
                a = exp2f(de.y * cA); h = fmaf(a, h, dx.y * Bq.y); pc = h * Cq.y;
                pc = DPP_ADD(pc, 0x101); pc = DPP_ADD(pc, 0x102);
                pc = DPP_ADD(pc, 0x104); pc = DPP_ADD(pc, 0x108);
                val.y = pc * gq.y;
                a = exp2f(de.z * cA); h = fmaf(a, h, dx.z * Bq.z); pc = h * Cq.z;
                pc = DPP_ADD(pc, 0x101); pc = DPP_ADD(pc, 0x102);
                pc = DPP_ADD(pc, 0x104); pc = DPP_ADD(pc, 0x108);
                val.z = pc * gq.z;
                a = exp2f(de.w * cA); h = fmaf(a, h, dx.w * Bq.w); pc = h * Cq.w;
                pc = DPP_ADD(pc, 0x101); pc = DPP_ADD(pc, 0x102);
                pc = DPP_ADD(pc, 0x104); pc = DPP_ADD(pc, 0x108);
                val.w = pc * gq.w;
                if (s == 0) *reinterpret_cast<float4*>(&syT[dd][4 * m]) = val;
            }
        }
        __syncthreads();

        // ---- C: fold over own-half d, write partial ----
        {
            float acc = 0.f;
#pragma unroll
            for (int k = 0; k < 4; ++k) {
                acc += syT[j8 * 4 + k][ll8];
            }
            acc += __shfl_xor(acc, 1);
            acc += __shfl_xor(acc, 2);
            acc += __shfl_xor(acc, 4);
            if (j8 == 0) {
                int i = ibase + ll8;
                int l = dir ? (511 - i) : i;
                float res = acc + sybase[ll8];
                // never-true data-dependent guard keeps spad observable
                if (sseq[0] == 1.0e38f) res += spad[tid];
                ypart[((c * 2 + half) * 32 + b) * 512 + l] = res;
            }
        }
        __syncthreads();
    }
}

__global__ __launch_bounds__(256) void kfinal(const float* __restrict__ xavg,
                                              const float* __restrict__ xmax,
                                              const float* __restrict__ ypart,
                                              const float* __restrict__ gate_w,
                                              const float* __restrict__ gate_b,
                                              const float* __restrict__ out_b,
                                              float* __restrict__ out) {
    const int idx = blockIdx.x * 256 + threadIdx.x;   // 0..16383
    float xa = xavg[idx], xm = xmax[idx];
    float alpha = 1.f / (1.f + __expf(-(fmaf(xa, gate_w[0], fmaf(xm, gate_w[1], gate_b[0])))));
    float sa = ypart[0 * 16384 + idx] + ypart[1 * 16384 + idx]
             + ypart[2 * 16384 + idx] + ypart[3 * 16384 + idx];
    float sm = ypart[4 * 16384 + idx] + ypart[5 * 16384 + idx]
             + ypart[6 * 16384 + idx] + ypart[7 * 16384 + idx];
    float y = alpha * sa + (1.f - alpha) * sm + out_b[0];
    out[idx] = 1.f / (1.f + __expf(-y));
}

extern "C" void kernel_launch(void* const* d_in, const int* in_sizes, int n_in,
                              void* d_out, int out_size, void* d_ws, size_t ws_size,
                              hipStream_t stream) {
    const float* inp = (const float*)d_in[0];
    const float* paw = (const float*)d_in[1];
    const float* pab = (const float*)d_in[2];
    const float* pmw = (const float*)d_in[3];
    const float* pmb = (const float*)d_in[4];
    const float* gw  = (const float*)d_in[5];
    const float* gb  = (const float*)d_in[6];
    const float* ow  = (const float*)d_in[7];
    const float* ob  = (const float*)d_in[8];

    float* ws = (float*)d_ws;
    float* xavg = ws;
    float* xmax = ws + 16384;
    float* ypart = ws + 32768;
    float* out = (float*)d_out;

    kreduce<<<16384, 256, 0, stream>>>(inp, xavg, xmax);
    kmamba<<<256, 512, 0, stream>>>(
        xavg, xmax, ypart, paw, pab, pmw, pmb, ow,
        (const float*)d_in[9],  (const float*)d_in[10], (const float*)d_in[11],
        (const float*)d_in[12], (const float*)d_in[13], (const float*)d_in[14],
        (const float*)d_in[15], (const float*)d_in[16], (const float*)d_in[17],
        (const float*)d_in[18], (const float*)d_in[19], (const float*)d_in[20],
        (const float*)d_in[21], (const float*)d_in[22], (const float*)d_in[23],
        (const float*)d_in[24], (const float*)d_in[25], (const float*)d_in[26]);
    kfinal<<<64, 256, 0, stream>>>(xavg, xmax, ypart, gw, gb, ob, out);
}

// Round 7
// 218.994 us; speedup vs baseline: 1.3248x; 1.3248x over previous
//
#include <hip/hip_runtime.h>
#include <math.h>

// ws layout (floats):
// [0, 16384)        x_avg[b][l]
// [16384, 32768)    x_max[b][l]
// [32768, 163840)   ypart[c*2+half][b][l]   (8 slots of 16384)
// [163840, +2359296) dbc[c][b][l][36]  record: [dt0,dt1, B0,C0,B1,C1,...,B15,C15, pad2]
#define RECW 36

__global__ __launch_bounds__(256) void kreduce(const float* __restrict__ in,
                                               float* __restrict__ xavg,
                                               float* __restrict__ xmax) {
    const int bl = blockIdx.x;            // 0..16383  (= b*512 + l)
    const float* p = in + (size_t)bl * 4096;
    const int t = threadIdx.x;
    float s = 0.f, m = -INFINITY;
#pragma unroll
    for (int it = 0; it < 4; ++it) {
        float4 v = *reinterpret_cast<const float4*>(p + (size_t)(it * 256 + t) * 4);
        s += v.x + v.y + v.z + v.w;
        m = fmaxf(m, fmaxf(fmaxf(v.x, v.y), fmaxf(v.z, v.w)));
    }
#pragma unroll
    for (int o = 1; o < 64; o <<= 1) {
        s += __shfl_xor(s, o);
        m = fmaxf(m, __shfl_xor(m, o));
    }
    __shared__ float ls[4], lm[4];
    const int w = t >> 6;
    if ((t & 63) == 0) { ls[w] = s; lm[w] = m; }
    __syncthreads();
    if (t == 0) {
        s = ls[0] + ls[1] + ls[2] + ls[3];
        m = fmaxf(fmaxf(lm[0], lm[1]), fmaxf(lm[2], lm[3]));
        xavg[bl] = s * (1.f / 4096.f);
        xmax[bl] = m;
    }
}

// slot of dbc j-index (j: 0,1=dt; 2..17=B; 18..33=C) in interleaved record
__device__ __forceinline__ int dbc_slot(int j) {
    return j < 2 ? j : (j < 18 ? 2 * j - 2 : 2 * j - 33);
}

// kprep: A-phases. One block per (call c, L-half). 512 threads.
__global__ __launch_bounds__(512) void kprep(
    const float* __restrict__ xavg, const float* __restrict__ xmax,
    float* __restrict__ dbc,
    const float* __restrict__ paw, const float* __restrict__ pab,
    const float* __restrict__ pmw, const float* __restrict__ pmb,
    const float* __restrict__ f_in_w, const float* __restrict__ f_conv_w,
    const float* __restrict__ f_conv_b, const float* __restrict__ f_xproj_w,
    const float* __restrict__ b_in_w, const float* __restrict__ b_conv_w,
    const float* __restrict__ b_conv_b, const float* __restrict__ b_xproj_w)
{
    const int tid = threadIdx.x;
    const int c = blockIdx.x >> 6;
    const int Lh = (blockIdx.x >> 5) & 1;
    const int b = blockIdx.x & 31;
    const int strm = c >> 1, dir = c & 1;
    const int Lbase = Lh * 256;

    const float* in_w = dir ? b_in_w   : f_in_w;
    const float* cwp  = dir ? b_conv_w : f_conv_w;
    const float* cbp  = dir ? b_conv_b : f_conv_b;
    const float* xpw  = dir ? b_xproj_w: f_xproj_w;
    const float* projw = strm ? pmw : paw;
    const float* projb = strm ? pmb : pab;
    const float* xin   = strm ? xmax : xavg;

    __shared__ float sseqP[260];      // x(Lbase-3+k), zeros for OOB
    __shared__ float su[64], sv[64];
    __shared__ float scw[64][4], scb[64];
    __shared__ float sxp[34][68];
    __shared__ float sxi[64][68];

    if (tid < 259) {
        int g = Lbase - 3 + tid;
        float val = 0.f;
        if (g >= 0) { int l = dir ? (511 - g) : g; val = xin[b * 512 + l]; }
        sseqP[tid] = val;
    }
    if (tid < 64) {
        float u = 0.f, v = 0.f;
        const float* row = in_w + tid * 32;
#pragma unroll
        for (int m = 0; m < 32; ++m) {
            u = fmaf(row[m], projw[m], u);
            v = fmaf(row[m], projb[m], v);
        }
        su[tid] = u; sv[tid] = v;
#pragma unroll
        for (int k = 0; k < 4; ++k) scw[tid][k] = cwp[tid * 4 + k];
        scb[tid] = cbp[tid];
    }
    for (int i = tid; i < 34 * 64; i += 512) sxp[i >> 6][i & 63] = xpw[i];
    __syncthreads();

    const int ll8 = tid >> 3;  // 0..63
    const int j8  = tid & 7;
    const int cb_idx = c * 32 + b;

    for (int chunk = 0; chunk < 4; ++chunk) {
        const int ibase = chunk * 64;
        const int li = ibase + ll8;
        const int gi = Lbase + li;

        // A1: xi for all 64 d
        {
            float t0 = sseqP[li], t1 = sseqP[li + 1], t2 = sseqP[li + 2], t3 = sseqP[li + 3];
            float vv0 = (gi >= 3) ? 1.f : 0.f;
            float vv1 = (gi >= 2) ? 1.f : 0.f;
            float vv2 = (gi >= 1) ? 1.f : 0.f;
#pragma unroll
            for (int k = 0; k < 8; ++k) {
                int di = j8 * 8 + k;
                float u = su[di], v = sv[di];
                float xc = scw[di][0] * fmaf(t0, u, vv0 * v)
                         + scw[di][1] * fmaf(t1, u, vv1 * v)
                         + scw[di][2] * fmaf(t2, u, vv2 * v)
                         + scw[di][3] * fmaf(t3, u, v);
                xc += scb[di];
                float sig = 1.f / (1.f + __expf(-xc));
                sxi[ll8][di] = xc * sig;
            }
        }
        __syncthreads();

        // A2: dbc = xi @ xproj_w.T -> global records (interleaved B/C layout)
        {
            float a0 = 0.f, a1 = 0.f, a2 = 0.f, a3 = 0.f, a4 = 0.f;
            const float4* xr4 = reinterpret_cast<const float4*>(&sxi[ll8][0]);
            const float4* r0 = reinterpret_cast<const float4*>(&sxp[j8 + 0][0]);
            const float4* r1 = reinterpret_cast<const float4*>(&sxp[j8 + 8][0]);
            const float4* r2 = reinterpret_cast<const float4*>(&sxp[j8 + 16][0]);
            const float4* r3 = reinterpret_cast<const float4*>(&sxp[j8 + 24][0]);
            const float4* r4 = (j8 < 2) ? reinterpret_cast<const float4*>(&sxp[j8 + 32][0]) : r0;
            bool extra = (j8 < 2);
#pragma unroll
            for (int q = 0; q < 16; ++q) {
                float4 x = xr4[q];
                float4 w;
                w = r0[q]; a0 = fmaf(x.x,w.x,fmaf(x.y,w.y,fmaf(x.z,w.z,fmaf(x.w,w.w,a0))));
                w = r1[q]; a1 = fmaf(x.x,w.x,fmaf(x.y,w.y,fmaf(x.z,w.z,fmaf(x.w,w.w,a1))));
                w = r2[q]; a2 = fmaf(x.x,w.x,fmaf(x.y,w.y,fmaf(x.z,w.z,fmaf(x.w,w.w,a2))));
                w = r3[q]; a3 = fmaf(x.x,w.x,fmaf(x.y,w.y,fmaf(x.z,w.z,fmaf(x.w,w.w,a3))));
                if (extra) { w = r4[q]; a4 = fmaf(x.x,w.x,fmaf(x.y,w.y,fmaf(x.z,w.z,fmaf(x.w,w.w,a4)))); }
            }
            float* rec = dbc + ((size_t)cb_idx * 512 + gi) * RECW;
            rec[dbc_slot(j8)]      = a0;
            rec[dbc_slot(j8 + 8)]  = a1;
            rec[dbc_slot(j8 + 16)] = a2;
            rec[dbc_slot(j8 + 24)] = a3;
            if (extra) rec[dbc_slot(j8 + 32)] = a4;
        }
        __syncthreads();
    }
}

// DPP add over 16-lane rows: after shl 1,2,4,8, lane (s==0) holds the row sum.
#define DPP_ADD(v, ctrl) ((v) + __int_as_float(__builtin_amdgcn_update_dpp(0, __float_as_int(v), (ctrl), 0xF, 0xF, true)))

// kscan: recurrence + output fold. One block per (c, half, b). 512 threads (dd,s).
__global__ __launch_bounds__(512) void kscan(
    const float* __restrict__ xavg, const float* __restrict__ xmax,
    const float* __restrict__ dbc, float* __restrict__ ypart,
    const float* __restrict__ paw, const float* __restrict__ pab,
    const float* __restrict__ pmw, const float* __restrict__ pmb,
    const float* __restrict__ outw_outer,
    const float* __restrict__ f_in_w, const float* __restrict__ f_conv_w,
    const float* __restrict__ f_conv_b, const float* __restrict__ f_dt_w,
    const float* __restrict__ f_dt_b, const float* __restrict__ f_A_log,
    const float* __restrict__ f_D, const float* __restrict__ f_out_w,
    const float* __restrict__ b_in_w, const float* __restrict__ b_conv_w,
    const float* __restrict__ b_conv_b, const float* __restrict__ b_dt_w,
    const float* __restrict__ b_dt_b, const float* __restrict__ b_A_log,
    const float* __restrict__ b_D, const float* __restrict__ b_out_w)
{
    const int tid = threadIdx.x;
    const int c = blockIdx.x >> 6;
    const int half = (blockIdx.x >> 5) & 1;
    const int b = blockIdx.x & 31;
    const int strm = c >> 1, dir = c & 1;

    const float* in_w = dir ? b_in_w   : f_in_w;
    const float* cwp  = dir ? b_conv_w : f_conv_w;
    const float* cbp  = dir ? b_conv_b : f_conv_b;
    const float* dtwp = dir ? b_dt_w   : f_dt_w;
    const float* dtbp = dir ? b_dt_b   : f_dt_b;
    const float* alog = dir ? b_A_log  : f_A_log;
    const float* Dpar = dir ? b_D      : f_D;
    const float* owp  = dir ? b_out_w  : f_out_w;
    const float* projw = strm ? pmw : paw;
    const float* projb = strm ? pmb : pab;
    const float* xin   = strm ? xmax : xavg;

    __shared__ float sseqP[516];      // 3 zeros + x(0..511) in scan order
    __shared__ float scon[32][17];    // per-dd consts (pad 17: conflict-free strided reads)
    __shared__ float sdbc[64][RECW];  // staged records for chunk
    __shared__ float sq[64][132];     // per (t,dd): {delta, delta*xi, g, g*D*xi}
    __shared__ float syT[64][36];     // scan outputs per (t,dd)

    sseqP[tid + 3] = xin[b * 512 + (dir ? (511 - tid) : tid)];
    if (tid < 3) sseqP[tid] = 0.f;
    if (tid < 32) {
        int ddz = tid, d = half * 32 + ddz;
        const float* rowx = in_w + d * 32;
        const float* rowz = in_w + (64 + d) * 32;
        float u = 0.f, v = 0.f, u2 = 0.f, v2 = 0.f, wf = 0.f;
#pragma unroll
        for (int m = 0; m < 32; ++m) {
            u  = fmaf(rowx[m], projw[m], u);
            v  = fmaf(rowx[m], projb[m], v);
            u2 = fmaf(rowz[m], projw[m], u2);
            v2 = fmaf(rowz[m], projb[m], v2);
            wf = fmaf(outw_outer[m], owp[m * 64 + d], wf);
        }
        scon[ddz][0] = cwp[d * 4 + 0];
        scon[ddz][1] = cwp[d * 4 + 1];
        scon[ddz][2] = cwp[d * 4 + 2];
        scon[ddz][3] = cwp[d * 4 + 3];
        scon[ddz][4] = cbp[d];
        scon[ddz][5] = u;  scon[ddz][6] = v;
        scon[ddz][7] = dtwp[d * 2]; scon[ddz][8] = dtwp[d * 2 + 1]; scon[ddz][9] = dtbp[d];
        scon[ddz][10] = u2; scon[ddz][11] = v2;
        scon[ddz][12] = wf; scon[ddz][13] = Dpar[d];
    }

    const int dd = tid >> 4;          // 0..31
    const int s  = tid & 15;          // 0..15
    const int d  = half * 32 + dd;
    const float cA = -expf(alog[d * 16 + s]) * 1.44269504088896340736f;
    float h = 0.f;

    const int tt8 = tid >> 3;         // 0..63 (precompute/fold row)
    const int j8  = tid & 7;
    const int cb_idx = c * 32 + b;
    const float* dbcB = dbc + (size_t)cb_idx * 512 * RECW;
    __syncthreads();

    for (int chunk = 0; chunk < 8; ++chunk) {
        const int ibase = chunk * 64;

        // stage 64 records (2304 floats, coalesced)
        {
            const float4* src = reinterpret_cast<const float4*>(dbcB + (size_t)ibase * RECW);
            float4* dst = reinterpret_cast<float4*>(&sdbc[0][0]);
            dst[tid] = src[tid];
            if (tid < 64) dst[512 + tid] = src[512 + tid];
        }
        __syncthreads();

        // precompute sq[t][dd] = {delta, delta*xi, g, g*D*xi}
        {
            const int t = ibase + tt8;
            float x0 = sseqP[t], x1 = sseqP[t + 1], x2 = sseqP[t + 2], x3 = sseqP[t + 3];
            float vv0 = (t >= 3) ? 1.f : 0.f;
            float vv1 = (t >= 2) ? 1.f : 0.f;
            float vv2 = (t >= 1) ? 1.f : 0.f;
            float dt0 = sdbc[tt8][0], dt1 = sdbc[tt8][1];
#pragma unroll
            for (int k = 0; k < 4; ++k) {
                int dq = j8 * 4 + k;
                float cw0 = scon[dq][0], cw1 = scon[dq][1], cw2 = scon[dq][2], cw3 = scon[dq][3];
                float cb  = scon[dq][4];
                float u = scon[dq][5], v = scon[dq][6];
                float dw0 = scon[dq][7], dw1 = scon[dq][8], dbv = scon[dq][9];
                float u2 = scon[dq][10], v2 = scon[dq][11];
                float wf = scon[dq][12], Dd = scon[dq][13];
                float xc = cw0 * fmaf(x0, u, vv0 * v)
                         + cw1 * fmaf(x1, u, vv1 * v)
                         + cw2 * fmaf(x2, u, vv2 * v)
                         + cw3 * fmaf(x3, u, v) + cb;
                float xi = xc / (1.f + __expf(-xc));
                float pre = fmaf(dt0, dw0, fmaf(dt1, dw1, dbv));
                float sp = (pre > 20.f) ? pre : log1pf(__expf(pre));
                float zv = fmaf(x3, u2, v2);
                float g = (zv / (1.f + __expf(-zv))) * wf;
                float4 q;
                q.x = sp; q.y = sp * xi; q.z = g; q.w = g * Dd * xi;
                *reinterpret_cast<float4*>(&sq[tt8][4 * dq]) = q;
            }
        }
        __syncthreads();

        // scan: 64 steps, h carried in-register across chunks
        for (int tt = 0; tt < 64; ++tt) {
            float4 q = *reinterpret_cast<const float4*>(&sq[tt][4 * dd]);
            float2 bc = *reinterpret_cast<const float2*>(&sdbc[tt][2 + 2 * s]);
            float a = exp2f(q.x * cA);
            h = fmaf(a, h, q.y * bc.x);
            float pc = h * bc.y;
            pc = DPP_ADD(pc, 0x101); pc = DPP_ADD(pc, 0x102);
            pc = DPP_ADD(pc, 0x104); pc = DPP_ADD(pc, 0x108);
            if (s == 0) syT[tt][dd] = fmaf(pc, q.z, q.w);
        }
        __syncthreads();

        // fold over 32 dd -> scalar partial
        {
            float acc = syT[tt8][j8 * 4] + syT[tt8][j8 * 4 + 1]
                      + syT[tt8][j8 * 4 + 2] + syT[tt8][j8 * 4 + 3];
            acc += __shfl_xor(acc, 1);
            acc += __shfl_xor(acc, 2);
            acc += __shfl_xor(acc, 4);
            if (j8 == 0) {
                int i = ibase + tt8;
                int l = dir ? (511 - i) : i;
                ypart[((c * 2 + half) * 32 + b) * 512 + l] = acc;
            }
        }
        __syncthreads();
    }
}

__global__ __launch_bounds__(256) void kfinal(const float* __restrict__ xavg,
                                              const float* __restrict__ xmax,
                                              const float* __restrict__ ypart,
                                              const float* __restrict__ gate_w,
                                              const float* __restrict__ gate_b,
                                              const float* __restrict__ out_b,
                                              float* __restrict__ out) {
    const int idx = blockIdx.x * 256 + threadIdx.x;   // 0..16383
    float xa = xavg[idx], xm = xmax[idx];
    float alpha = 1.f / (1.f + __expf(-(fmaf(xa, gate_w[0], fmaf(xm, gate_w[1], gate_b[0])))));
    float sa = ypart[0 * 16384 + idx] + ypart[1 * 16384 + idx]
             + ypart[2 * 16384 + idx] + ypart[3 * 16384 + idx];
    float sm = ypart[4 * 16384 + idx] + ypart[5 * 16384 + idx]
             + ypart[6 * 16384 + idx] + ypart[7 * 16384 + idx];
    float y = alpha * sa + (1.f - alpha) * sm + out_b[0];
    out[idx] = 1.f / (1.f + __expf(-y));
}

extern "C" void kernel_launch(void* const* d_in, const int* in_sizes, int n_in,
                              void* d_out, int out_size, void* d_ws, size_t ws_size,
                              hipStream_t stream) {
    const float* inp = (const float*)d_in[0];
    const float* paw = (const float*)d_in[1];
    const float* pab = (const float*)d_in[2];
    const float* pmw = (const float*)d_in[3];
    const float* pmb = (const float*)d_in[4];
    const float* gw  = (const float*)d_in[5];
    const float* gb  = (const float*)d_in[6];
    const float* ow  = (const float*)d_in[7];
    const float* ob  = (const float*)d_in[8];

    float* ws = (float*)d_ws;
    float* xavg = ws;
    float* xmax = ws + 16384;
    float* ypart = ws + 32768;
    float* dbc = ws + 163840;
    float* out = (float*)d_out;

    kreduce<<<16384, 256, 0, stream>>>(inp, xavg, xmax);
    kprep<<<256, 512, 0, stream>>>(
        xavg, xmax, dbc, paw, pab, pmw, pmb,
        (const float*)d_in[9],  (const float*)d_in[10], (const float*)d_in[11], (const float*)d_in[12],
        (const float*)d_in[18], (const float*)d_in[19], (const float*)d_in[20], (const float*)d_in[21]);
    kscan<<<256, 512, 0, stream>>>(
        xavg, xmax, dbc, ypart, paw, pab, pmw, pmb, ow,
        (const float*)d_in[9],  (const float*)d_in[10], (const float*)d_in[11],
        (const float*)d_in[13], (const float*)d_in[14], (const float*)d_in[15],
        (const float*)d_in[16], (const float*)d_in[17],
        (const float*)d_in[18], (const float*)d_in[19], (const float*)d_in[20],
        (const float*)d_in[22], (const float*)d_in[23], (const float*)d_in[24],
        (const float*)d_in[25], (const float*)d_in[26]);
    kfinal<<<64, 256, 0, stream>>>(xavg, xmax, ypart, gw, gb, ob, out);
}

// Round 8
// 193.145 us; speedup vs baseline: 1.5021x; 1.1338x over previous
//
#include <hip/hip_runtime.h>
#include <math.h>

// ws layout (floats):
// [0, 16384)        x_avg[b][l]
// [16384, 32768)    x_max[b][l]
// [32768, 163840)   ypart[c*2+half][b][l]   (8 slots of 16384)
// [163840, +2359296) dbc[c][b][l][36]  record: [dt0,dt1, B0,C0,B1,C1,...,B15,C15, pad2]
#define RECW 36

__global__ __launch_bounds__(256) void kreduce(const float* __restrict__ in,
                                               float* __restrict__ xavg,
                                               float* __restrict__ xmax) {
    const int bl = blockIdx.x;            // 0..16383  (= b*512 + l)
    const float* p = in + (size_t)bl * 4096;
    const int t = threadIdx.x;
    float s = 0.f, m = -INFINITY;
#pragma unroll
    for (int it = 0; it < 4; ++it) {
        float4 v = *reinterpret_cast<const float4*>(p + (size_t)(it * 256 + t) * 4);
        s += v.x + v.y + v.z + v.w;
        m = fmaxf(m, fmaxf(fmaxf(v.x, v.y), fmaxf(v.z, v.w)));
    }
#pragma unroll
    for (int o = 1; o < 64; o <<= 1) {
        s += __shfl_xor(s, o);
        m = fmaxf(m, __shfl_xor(m, o));
    }
    __shared__ float ls[4], lm[4];
    const int w = t >> 6;
    if ((t & 63) == 0) { ls[w] = s; lm[w] = m; }
    __syncthreads();
    if (t == 0) {
        s = ls[0] + ls[1] + ls[2] + ls[3];
        m = fmaxf(fmaxf(lm[0], lm[1]), fmaxf(lm[2], lm[3]));
        xavg[bl] = s * (1.f / 4096.f);
        xmax[bl] = m;
    }
}

// slot of dbc j-index (j: 0,1=dt; 2..17=B; 18..33=C) in interleaved record
__device__ __forceinline__ int dbc_slot(int j) {
    return j < 2 ? j : (j < 18 ? 2 * j - 2 : 2 * j - 33);
}

// kprep: A-phases. One block per (call c, L-half, batch). 512 threads. (unchanged from r7)
__global__ __launch_bounds__(512) void kprep(
    const float* __restrict__ xavg, const float* __restrict__ xmax,
    float* __restrict__ dbc,
    const float* __restrict__ paw, const float* __restrict__ pab,
    const float* __restrict__ pmw, const float* __restrict__ pmb,
    const float* __restrict__ f_in_w, const float* __restrict__ f_conv_w,
    const float* __restrict__ f_conv_b, const float* __restrict__ f_xproj_w,
    const float* __restrict__ b_in_w, const float* __restrict__ b_conv_w,
    const float* __restrict__ b_conv_b, const float* __restrict__ b_xproj_w)
{
    const int tid = threadIdx.x;
    const int c = blockIdx.x >> 6;
    const int Lh = (blockIdx.x >> 5) & 1;
    const int b = blockIdx.x & 31;
    const int strm = c >> 1, dir = c & 1;
    const int Lbase = Lh * 256;

    const float* in_w = dir ? b_in_w   : f_in_w;
    const float* cwp  = dir ? b_conv_w : f_conv_w;
    const float* cbp  = dir ? b_conv_b : f_conv_b;
    const float* xpw  = dir ? b_xproj_w: f_xproj_w;
    const float* projw = strm ? pmw : paw;
    const float* projb = strm ? pmb : pab;
    const float* xin   = strm ? xmax : xavg;

    __shared__ float sseqP[260];      // x(Lbase-3+k), zeros for OOB
    __shared__ float su[64], sv[64];
    __shared__ float scw[64][4], scb[64];
    __shared__ float sxp[34][68];
    __shared__ float sxi[64][68];

    if (tid < 259) {
        int g = Lbase - 3 + tid;
        float val = 0.f;
        if (g >= 0) { int l = dir ? (511 - g) : g; val = xin[b * 512 + l]; }
        sseqP[tid] = val;
    }
    if (tid < 64) {
        float u = 0.f, v = 0.f;
        const float* row = in_w + tid * 32;
#pragma unroll
        for (int m = 0; m < 32; ++m) {
            u = fmaf(row[m], projw[m], u);
            v = fmaf(row[m], projb[m], v);
        }
        su[tid] = u; sv[tid] = v;
#pragma unroll
        for (int k = 0; k < 4; ++k) scw[tid][k] = cwp[tid * 4 + k];
        scb[tid] = cbp[tid];
    }
    for (int i = tid; i < 34 * 64; i += 512) sxp[i >> 6][i & 63] = xpw[i];
    __syncthreads();

    const int ll8 = tid >> 3;  // 0..63
    const int j8  = tid & 7;
    const int cb_idx = c * 32 + b;

    for (int chunk = 0; chunk < 4; ++chunk) {
        const int ibase = chunk * 64;
        const int li = ibase + ll8;
        const int gi = Lbase + li;

        // A1: xi for all 64 d
        {
            float t0 = sseqP[li], t1 = sseqP[li + 1], t2 = sseqP[li + 2], t3 = sseqP[li + 3];
            float vv0 = (gi >= 3) ? 1.f : 0.f;
            float vv1 = (gi >= 2) ? 1.f : 0.f;
            float vv2 = (gi >= 1) ? 1.f : 0.f;
#pragma unroll
            for (int k = 0; k < 8; ++k) {
                int di = j8 * 8 + k;
                float u = su[di], v = sv[di];
                float xc = scw[di][0] * fmaf(t0, u, vv0 * v)
                         + scw[di][1] * fmaf(t1, u, vv1 * v)
                         + scw[di][2] * fmaf(t2, u, vv2 * v)
                         + scw[di][3] * fmaf(t3, u, v);
                xc += scb[di];
                float sig = 1.f / (1.f + __expf(-xc));
                sxi[ll8][di] = xc * sig;
            }
        }
        __syncthreads();

        // A2: dbc = xi @ xproj_w.T -> global records (interleaved B/C layout)
        {
            float a0 = 0.f, a1 = 0.f, a2 = 0.f, a3 = 0.f, a4 = 0.f;
            const float4* xr4 = reinterpret_cast<const float4*>(&sxi[ll8][0]);
            const float4* r0 = reinterpret_cast<const float4*>(&sxp[j8 + 0][0]);
            const float4* r1 = reinterpret_cast<const float4*>(&sxp[j8 + 8][0]);
            const float4* r2 = reinterpret_cast<const float4*>(&sxp[j8 + 16][0]);
            const float4* r3 = reinterpret_cast<const float4*>(&sxp[j8 + 24][0]);
            const float4* r4 = (j8 < 2) ? reinterpret_cast<const float4*>(&sxp[j8 + 32][0]) : r0;
            bool extra = (j8 < 2);
#pragma unroll
            for (int q = 0; q < 16; ++q) {
                float4 x = xr4[q];
                float4 w;
                w = r0[q]; a0 = fmaf(x.x,w.x,fmaf(x.y,w.y,fmaf(x.z,w.z,fmaf(x.w,w.w,a0))));
                w = r1[q]; a1 = fmaf(x.x,w.x,fmaf(x.y,w.y,fmaf(x.z,w.z,fmaf(x.w,w.w,a1))));
                w = r2[q]; a2 = fmaf(x.x,w.x,fmaf(x.y,w.y,fmaf(x.z,w.z,fmaf(x.w,w.w,a2))));
                w = r3[q]; a3 = fmaf(x.x,w.x,fmaf(x.y,w.y,fmaf(x.z,w.z,fmaf(x.w,w.w,a3))));
                if (extra) { w = r4[q]; a4 = fmaf(x.x,w.x,fmaf(x.y,w.y,fmaf(x.z,w.z,fmaf(x.w,w.w,a4)))); }
            }
            float* rec = dbc + ((size_t)cb_idx * 512 + gi) * RECW;
            rec[dbc_slot(j8)]      = a0;
            rec[dbc_slot(j8 + 8)]  = a1;
            rec[dbc_slot(j8 + 16)] = a2;
            rec[dbc_slot(j8 + 24)] = a3;
            if (extra) rec[dbc_slot(j8 + 32)] = a4;
        }
        __syncthreads();
    }
}

// DPP add over 16-lane rows: after shl 1,2,4,8, lane (s==0) holds the row sum.
#define DPP_ADD(v, ctrl) ((v) + __int_as_float(__builtin_amdgcn_update_dpp(0, __float_as_int(v), (ctrl), 0xF, 0xF, true)))

// kscan: recurrence + output fold. One block per (c, half, b). 512 threads (dd,s).
// Scan phase uses r5's proven layout: transposed [dd][t] b128 operands (4 steps/read),
// B/C as aligned float2 from the staged record (row pad 38 -> 8B-aligned, conflict-free).
__global__ __launch_bounds__(512) void kscan(
    const float* __restrict__ xavg, const float* __restrict__ xmax,
    const float* __restrict__ dbc, float* __restrict__ ypart,
    const float* __restrict__ paw, const float* __restrict__ pab,
    const float* __restrict__ pmw, const float* __restrict__ pmb,
    const float* __restrict__ outw_outer,
    const float* __restrict__ f_in_w, const float* __restrict__ f_conv_w,
    const float* __restrict__ f_conv_b, const float* __restrict__ f_dt_w,
    const float* __restrict__ f_dt_b, const float* __restrict__ f_A_log,
    const float* __restrict__ f_D, const float* __restrict__ f_out_w,
    const float* __restrict__ b_in_w, const float* __restrict__ b_conv_w,
    const float* __restrict__ b_conv_b, const float* __restrict__ b_dt_w,
    const float* __restrict__ b_dt_b, const float* __restrict__ b_A_log,
    const float* __restrict__ b_D, const float* __restrict__ b_out_w)
{
    const int tid = threadIdx.x;
    const int c = blockIdx.x >> 6;
    const int half = (blockIdx.x >> 5) & 1;
    const int b = blockIdx.x & 31;
    const int strm = c >> 1, dir = c & 1;

    const float* in_w = dir ? b_in_w   : f_in_w;
    const float* cwp  = dir ? b_conv_w : f_conv_w;
    const float* cbp  = dir ? b_conv_b : f_conv_b;
    const float* dtwp = dir ? b_dt_w   : f_dt_w;
    const float* dtbp = dir ? b_dt_b   : f_dt_b;
    const float* alog = dir ? b_A_log  : f_A_log;
    const float* Dpar = dir ? b_D      : f_D;
    const float* owp  = dir ? b_out_w  : f_out_w;
    const float* projw = strm ? pmw : paw;
    const float* projb = strm ? pmb : pab;
    const float* xin   = strm ? xmax : xavg;

    __shared__ float sseqP[516];      // 3 zeros + x(0..511) in scan order
    __shared__ float scon[32][17];    // per-dd consts
    __shared__ float sraw[64][38];    // staged records, pad 38 (even -> 8B-aligned float2)
    __shared__ float sdT[32][68];     // delta, transposed [dd][t]
    __shared__ float sxT[32][68];     // delta*xi, transposed
    __shared__ float sgT[32][68];     // g = silu(z)*wfold, transposed
    __shared__ float syT[32][68];     // scan outputs, transposed
    __shared__ float sybase[64];      // per-t Sum_dd g*D*xi

    sseqP[tid + 3] = xin[b * 512 + (dir ? (511 - tid) : tid)];
    if (tid < 3) sseqP[tid] = 0.f;
    if (tid < 32) {
        int ddz = tid, d = half * 32 + ddz;
        const float* rowx = in_w + d * 32;
        const float* rowz = in_w + (64 + d) * 32;
        float u = 0.f, v = 0.f, u2 = 0.f, v2 = 0.f, wf = 0.f;
#pragma unroll
        for (int m = 0; m < 32; ++m) {
            u  = fmaf(rowx[m], projw[m], u);
            v  = fmaf(rowx[m], projb[m], v);
            u2 = fmaf(rowz[m], projw[m], u2);
            v2 = fmaf(rowz[m], projb[m], v2);
            wf = fmaf(outw_outer[m], owp[m * 64 + d], wf);
        }
        scon[ddz][0] = cwp[d * 4 + 0];
        scon[ddz][1] = cwp[d * 4 + 1];
        scon[ddz][2] = cwp[d * 4 + 2];
        scon[ddz][3] = cwp[d * 4 + 3];
        scon[ddz][4] = cbp[d];
        scon[ddz][5] = u;  scon[ddz][6] = v;
        scon[ddz][7] = dtwp[d * 2]; scon[ddz][8] = dtwp[d * 2 + 1]; scon[ddz][9] = dtbp[d];
        scon[ddz][10] = u2; scon[ddz][11] = v2;
        scon[ddz][12] = wf; scon[ddz][13] = Dpar[d];
    }

    const int dd = tid >> 4;          // 0..31
    const int s  = tid & 15;          // 0..15
    const int d  = half * 32 + dd;
    const float cA = -expf(alog[d * 16 + s]) * 1.44269504088896340736f;
    float h = 0.f;

    const int tt8 = tid >> 3;         // 0..63 (precompute/fold row)
    const int j8  = tid & 7;
    const int cb_idx = c * 32 + b;
    const float* dbcB = dbc + (size_t)cb_idx * 512 * RECW;
    __syncthreads();

    for (int chunk = 0; chunk < 8; ++chunk) {
        const int ibase = chunk * 64;

        // stage 64 records (2304 floats, coalesced global, padded LDS rows)
        {
            const float* src = dbcB + (size_t)ibase * RECW;
#pragma unroll
            for (int i = tid; i < 64 * RECW; i += 512) {
                sraw[i / RECW][i % RECW] = src[i];
            }
        }
        __syncthreads();

        // precompute transposed per-(t,dd) quantities + sybase
        {
            const int t = ibase + tt8;
            float x0 = sseqP[t], x1 = sseqP[t + 1], x2 = sseqP[t + 2], x3 = sseqP[t + 3];
            float vv0 = (t >= 3) ? 1.f : 0.f;
            float vv1 = (t >= 2) ? 1.f : 0.f;
            float vv2 = (t >= 1) ? 1.f : 0.f;
            float dt0 = sraw[tt8][0], dt1 = sraw[tt8][1];
            float ybp = 0.f;
#pragma unroll
            for (int k = 0; k < 4; ++k) {
                int dq = j8 * 4 + k;
                float cw0 = scon[dq][0], cw1 = scon[dq][1], cw2 = scon[dq][2], cw3 = scon[dq][3];
                float cb  = scon[dq][4];
                float u = scon[dq][5], v = scon[dq][6];
                float dw0 = scon[dq][7], dw1 = scon[dq][8], dbv = scon[dq][9];
                float u2 = scon[dq][10], v2 = scon[dq][11];
                float wf = scon[dq][12], Dd = scon[dq][13];
                float xc = cw0 * fmaf(x0, u, vv0 * v)
                         + cw1 * fmaf(x1, u, vv1 * v)
                         + cw2 * fmaf(x2, u, vv2 * v)
                         + cw3 * fmaf(x3, u, v) + cb;
                float xi = xc / (1.f + __expf(-xc));
                float pre = fmaf(dt0, dw0, fmaf(dt1, dw1, dbv));
                float sp = (pre > 20.f) ? pre : log1pf(__expf(pre));
                float zv = fmaf(x3, u2, v2);
                float g = (zv / (1.f + __expf(-zv))) * wf;
                sdT[dq][tt8] = sp;
                sxT[dq][tt8] = sp * xi;
                sgT[dq][tt8] = g;
                ybp = fmaf(g * Dd, xi, ybp);
            }
            ybp += __shfl_xor(ybp, 1);
            ybp += __shfl_xor(ybp, 2);
            ybp += __shfl_xor(ybp, 4);
            if (j8 == 0) sybase[tt8] = ybp;
        }
        __syncthreads();

        // scan: 16 m-iters x 4 steps; h carried in-register across chunks
        {
            const float4* dT = reinterpret_cast<const float4*>(&sdT[dd][0]);
            const float4* xT = reinterpret_cast<const float4*>(&sxT[dd][0]);
            const float4* gT = reinterpret_cast<const float4*>(&sgT[dd][0]);
#pragma unroll 2
            for (int m = 0; m < 16; ++m) {
                float4 de = dT[m], dx = xT[m], gq = gT[m];
                float2 bc0 = *reinterpret_cast<const float2*>(&sraw[4 * m + 0][2 + 2 * s]);
                float2 bc1 = *reinterpret_cast<const float2*>(&sraw[4 * m + 1][2 + 2 * s]);
                float2 bc2 = *reinterpret_cast<const float2*>(&sraw[4 * m + 2][2 + 2 * s]);
                float2 bc3 = *reinterpret_cast<const float2*>(&sraw[4 * m + 3][2 + 2 * s]);
                float4 val;
                float a, pc;
                a = exp2f(de.x * cA); h = fmaf(a, h, dx.x * bc0.x); pc = h * bc0.y;
                pc = DPP_ADD(pc, 0x101); pc = DPP_ADD(pc, 0x102);
                pc = DPP_ADD(pc, 0x104); pc = DPP_ADD(pc, 0x108);
                val.x = pc * gq.x;
                a = exp2f(de.y * cA); h = fmaf(a, h, dx.y * bc1.x); pc = h * bc1.y;
                pc = DPP_ADD(pc, 0x101); pc = DPP_ADD(pc, 0x102);
                pc = DPP_ADD(pc, 0x104); pc = DPP_ADD(pc, 0x108);
                val.y = pc * gq.y;
                a = exp2f(de.z * cA); h = fmaf(a, h, dx.z * bc2.x); pc = h * bc2.y;
                pc = DPP_ADD(pc, 0x101); pc = DPP_ADD(pc, 0x102);
                pc = DPP_ADD(pc, 0x104); pc = DPP_ADD(pc, 0x108);
                val.z = pc * gq.z;
                a = exp2f(de.w * cA); h = fmaf(a, h, dx.w * bc3.x); pc = h * bc3.y;
                pc = DPP_ADD(pc, 0x101); pc = DPP_ADD(pc, 0x102);
                pc = DPP_ADD(pc, 0x104); pc = DPP_ADD(pc, 0x108);
                val.w = pc * gq.w;
                if (s == 0) *reinterpret_cast<float4*>(&syT[dd][4 * m]) = val;
            }
        }
        __syncthreads();

        // fold over 32 dd -> scalar partial
        {
            float acc = syT[j8 * 4][tt8] + syT[j8 * 4 + 1][tt8]
                      + syT[j8 * 4 + 2][tt8] + syT[j8 * 4 + 3][tt8];
            acc += __shfl_xor(acc, 1);
            acc += __shfl_xor(acc, 2);
            acc += __shfl_xor(acc, 4);
            if (j8 == 0) {
                int i = ibase + tt8;
                int l = dir ? (511 - i) : i;
                ypart[((c * 2 + half) * 32 + b) * 512 + l] = acc + sybase[tt8];
            }
        }
        __syncthreads();
    }
}

__global__ __launch_bounds__(256) void kfinal(const float* __restrict__ xavg,
                                              const float* __restrict__ xmax,
                                              const float* __restrict__ ypart,
                                              const float* __restrict__ gate_w,
                                              const float* __restrict__ gate_b,
                                              const float* __restrict__ out_b,
                                              float* __restrict__ out) {
    const int idx = blockIdx.x * 256 + threadIdx.x;   // 0..16383
    float xa = xavg[idx], xm = xmax[idx];
    float alpha = 1.f / (1.f + __expf(-(fmaf(xa, gate_w[0], fmaf(xm, gate_w[1], gate_b[0])))));
    float sa = ypart[0 * 16384 + idx] + ypart[1 * 16384 + idx]
             + ypart[2 * 16384 + idx] + ypart[3 * 16384 + idx];
    float sm = ypart[4 * 16384 + idx] + ypart[5 * 16384 + idx]
             + ypart[6 * 16384 + idx] + ypart[7 * 16384 + idx];
    float y = alpha * sa + (1.f - alpha) * sm + out_b[0];
    out[idx] = 1.f / (1.f + __expf(-y));
}

extern "C" void kernel_launch(void* const* d_in, const int* in_sizes, int n_in,
                              void* d_out, int out_size, void* d_ws, size_t ws_size,
                              hipStream_t stream) {
    const float* inp = (const float*)d_in[0];
    const float* paw = (const float*)d_in[1];
    const float* pab = (const float*)d_in[2];
    const float* pmw = (const float*)d_in[3];
    const float* pmb = (const float*)d_in[4];
    const float* gw  = (const float*)d_in[5];
    const float* gb  = (const float*)d_in[6];
    const float* ow  = (const float*)d_in[7];
    const float* ob  = (const float*)d_in[8];

    float* ws = (float*)d_ws;
    float* xavg = ws;
    float* xmax = ws + 16384;
    float* ypart = ws + 32768;
    float* dbc = ws + 163840;
    float* out = (float*)d_out;

    kreduce<<<16384, 256, 0, stream>>>(inp, xavg, xmax);
    kprep<<<256, 512, 0, stream>>>(
        xavg, xmax, dbc, paw, pab, pmw, pmb,
        (const float*)d_in[9],  (const float*)d_in[10], (const float*)d_in[11], (const float*)d_in[12],
        (const float*)d_in[18], (const float*)d_in[19], (const float*)d_in[20], (const float*)d_in[21]);
    kscan<<<256, 512, 0, stream>>>(
        xavg, xmax, dbc, ypart, paw, pab, pmw, pmb, ow,
        (const float*)d_in[9],  (const float*)d_in[10], (const float*)d_in[11],
        (const float*)d_in[13], (const float*)d_in[14], (const float*)d_in[15],
        (const float*)d_in[16], (const float*)d_in[17],
        (const float*)d_in[18], (const float*)d_in[19], (const float*)d_in[20],
        (const float*)d_in[22], (const float*)d_in[23], (const float*)d_in[24],
        (const float*)d_in[25], (const float*)d_in[26]);
    kfinal<<<64, 256, 0, stream>>>(xavg, xmax, ypart, gw, gb, ob, out);
}

// Round 9
// 140.886 us; speedup vs baseline: 2.0593x; 1.3709x over previous
//
#include <hip/hip_runtime.h>
#include <math.h>

// ws layout (floats):
// [0, 16384)        x_avg[b][l]
// [16384, 32768)    x_max[b][l]
// [32768, 163840)   ypart[c*2+half][b][l]   (8 slots of 16384)
// [163840, +2359296) dbc[c][b][l][36]  record: [dt0,dt1, B0,C0,B1,C1,...,B15,C15, pad2]
#define RECW 36

__global__ __launch_bounds__(256) void kreduce(const float* __restrict__ in,
                                               float* __restrict__ xavg,
                                               float* __restrict__ xmax) {
    const int bl = blockIdx.x;            // 0..16383  (= b*512 + l)
    const float* p = in + (size_t)bl * 4096;
    const int t = threadIdx.x;
    float s = 0.f, m = -INFINITY;
#pragma unroll
    for (int it = 0; it < 4; ++it) {
        float4 v = *reinterpret_cast<const float4*>(p + (size_t)(it * 256 + t) * 4);
        s += v.x + v.y + v.z + v.w;
        m = fmaxf(m, fmaxf(fmaxf(v.x, v.y), fmaxf(v.z, v.w)));
    }
#pragma unroll
    for (int o = 1; o < 64; o <<= 1) {
        s += __shfl_xor(s, o);
        m = fmaxf(m, __shfl_xor(m, o));
    }
    __shared__ float ls[4], lm[4];
    const int w = t >> 6;
    if ((t & 63) == 0) { ls[w] = s; lm[w] = m; }
    __syncthreads();
    if (t == 0) {
        s = ls[0] + ls[1] + ls[2] + ls[3];
        m = fmaxf(fmaxf(lm[0], lm[1]), fmaxf(lm[2], lm[3]));
        xavg[bl] = s * (1.f / 4096.f);
        xmax[bl] = m;
    }
}

// slot of dbc j-index (j: 0,1=dt; 2..17=B; 18..33=C) in interleaved record
__device__ __forceinline__ int dbc_slot(int j) {
    return j < 2 ? j : (j < 18 ? 2 * j - 2 : 2 * j - 33);
}

// kprep: A-phases. One block per (call c, L-half, batch). 512 threads.
__global__ __launch_bounds__(512) void kprep(
    const float* __restrict__ xavg, const float* __restrict__ xmax,
    float* __restrict__ dbc,
    const float* __restrict__ paw, const float* __restrict__ pab,
    const float* __restrict__ pmw, const float* __restrict__ pmb,
    const float* __restrict__ f_in_w, const float* __restrict__ f_conv_w,
    const float* __restrict__ f_conv_b, const float* __restrict__ f_xproj_w,
    const float* __restrict__ b_in_w, const float* __restrict__ b_conv_w,
    const float* __restrict__ b_conv_b, const float* __restrict__ b_xproj_w)
{
    const int tid = threadIdx.x;
    const int c = blockIdx.x >> 6;
    const int Lh = (blockIdx.x >> 5) & 1;
    const int b = blockIdx.x & 31;
    const int strm = c >> 1, dir = c & 1;
    const int Lbase = Lh * 256;

    const float* in_w = dir ? b_in_w   : f_in_w;
    const float* cwp  = dir ? b_conv_w : f_conv_w;
    const float* cbp  = dir ? b_conv_b : f_conv_b;
    const float* xpw  = dir ? b_xproj_w: f_xproj_w;
    const float* projw = strm ? pmw : paw;
    const float* projb = strm ? pmb : pab;
    const float* xin   = strm ? xmax : xavg;

    __shared__ float sseqP[260];      // x(Lbase-3+k), zeros for OOB
    __shared__ float su[64], sv[64];
    __shared__ float scw[64][4], scb[64];
    __shared__ float sxp[34][68];
    __shared__ float sxi[64][68];

    if (tid < 259) {
        int g = Lbase - 3 + tid;
        float val = 0.f;
        if (g >= 0) { int l = dir ? (511 - g) : g; val = xin[b * 512 + l]; }
        sseqP[tid] = val;
    }
    if (tid < 64) {
        float u = 0.f, v = 0.f;
        const float* row = in_w + tid * 32;
#pragma unroll
        for (int m = 0; m < 32; ++m) {
            u = fmaf(row[m], projw[m], u);
            v = fmaf(row[m], projb[m], v);
        }
        su[tid] = u; sv[tid] = v;
#pragma unroll
        for (int k = 0; k < 4; ++k) scw[tid][k] = cwp[tid * 4 + k];
        scb[tid] = cbp[tid];
    }
    for (int i = tid; i < 34 * 64; i += 512) sxp[i >> 6][i & 63] = xpw[i];
    __syncthreads();

    const int ll8 = tid >> 3;  // 0..63
    const int j8  = tid & 7;
    const int cb_idx = c * 32 + b;

    for (int chunk = 0; chunk < 4; ++chunk) {
        const int ibase = chunk * 64;
        const int li = ibase + ll8;
        const int gi = Lbase + li;

        // A1: xi for all 64 d
        {
            float t0 = sseqP[li], t1 = sseqP[li + 1], t2 = sseqP[li + 2], t3 = sseqP[li + 3];
            float vv0 = (gi >= 3) ? 1.f : 0.f;
            float vv1 = (gi >= 2) ? 1.f : 0.f;
            float vv2 = (gi >= 1) ? 1.f : 0.f;
#pragma unroll
            for (int k = 0; k < 8; ++k) {
                int di = j8 * 8 + k;
                float u = su[di], v = sv[di];
                float xc = scw[di][0] * fmaf(t0, u, vv0 * v)
                         + scw[di][1] * fmaf(t1, u, vv1 * v)
                         + scw[di][2] * fmaf(t2, u, vv2 * v)
                         + scw[di][3] * fmaf(t3, u, v);
                xc += scb[di];
                float sig = 1.f / (1.f + __expf(-xc));
                sxi[ll8][di] = xc * sig;
            }
        }
        __syncthreads();

        // A2: dbc = xi @ xproj_w.T -> global records (interleaved B/C layout)
        // NOTE: unroll 2 (NOT full): full unroll hoists ~96 ds_read_b128 per
        // thread past the 128-VGPR budget -> scratch spill (the 600+ MB phantom
        // HBM traffic of rounds 2-8). ~12 b128 in flight is plenty of ILP.
        {
            float a0 = 0.f, a1 = 0.f, a2 = 0.f, a3 = 0.f, a4 = 0.f;
            const float4* xr4 = reinterpret_cast<const float4*>(&sxi[ll8][0]);
            const float4* r0 = reinterpret_cast<const float4*>(&sxp[j8 + 0][0]);
            const float4* r1 = reinterpret_cast<const float4*>(&sxp[j8 + 8][0]);
            const float4* r2 = reinterpret_cast<const float4*>(&sxp[j8 + 16][0]);
            const float4* r3 = reinterpret_cast<const float4*>(&sxp[j8 + 24][0]);
            const float4* r4 = (j8 < 2) ? reinterpret_cast<const float4*>(&sxp[j8 + 32][0]) : r0;
            bool extra = (j8 < 2);
#pragma unroll 2
            for (int q = 0; q < 16; ++q) {
                float4 x = xr4[q];
                float4 w;
                w = r0[q]; a0 = fmaf(x.x,w.x,fmaf(x.y,w.y,fmaf(x.z,w.z,fmaf(x.w,w.w,a0))));
                w = r1[q]; a1 = fmaf(x.x,w.x,fmaf(x.y,w.y,fmaf(x.z,w.z,fmaf(x.w,w.w,a1))));
                w = r2[q]; a2 = fmaf(x.x,w.x,fmaf(x.y,w.y,fmaf(x.z,w.z,fmaf(x.w,w.w,a2))));
                w = r3[q]; a3 = fmaf(x.x,w.x,fmaf(x.y,w.y,fmaf(x.z,w.z,fmaf(x.w,w.w,a3))));
                if (extra) { w = r4[q]; a4 = fmaf(x.x,w.x,fmaf(x.y,w.y,fmaf(x.z,w.z,fmaf(x.w,w.w,a4)))); }
            }
            float* rec = dbc + ((size_t)cb_idx * 512 + gi) * RECW;
            rec[dbc_slot(j8)]      = a0;
            rec[dbc_slot(j8 + 8)]  = a1;
            rec[dbc_slot(j8 + 16)] = a2;
            rec[dbc_slot(j8 + 24)] = a3;
            if (extra) rec[dbc_slot(j8 + 32)] = a4;
        }
        __syncthreads();
    }
}

// DPP add over 16-lane rows: after shl 1,2,4,8, lane (s==0) holds the row sum.
#define DPP_ADD(v, ctrl) ((v) + __int_as_float(__builtin_amdgcn_update_dpp(0, __float_as_int(v), (ctrl), 0xF, 0xF, true)))

// kscan: recurrence + output fold. One block per (c, half, b). 512 threads (dd,s).
__global__ __launch_bounds__(512) void kscan(
    const float* __restrict__ xavg, const float* __restrict__ xmax,
    const float* __restrict__ dbc, float* __restrict__ ypart,
    const float* __restrict__ paw, const float* __restrict__ pab,
    const float* __restrict__ pmw, const float* __restrict__ pmb,
    const float* __restrict__ outw_outer,
    const float* __restrict__ f_in_w, const float* __restrict__ f_conv_w,
    const float* __restrict__ f_conv_b, const float* __restrict__ f_dt_w,
    const float* __restrict__ f_dt_b, const float* __restrict__ f_A_log,
    const float* __restrict__ f_D, const float* __restrict__ f_out_w,
    const float* __restrict__ b_in_w, const float* __restrict__ b_conv_w,
    const float* __restrict__ b_conv_b, const float* __restrict__ b_dt_w,
    const float* __restrict__ b_dt_b, const float* __restrict__ b_A_log,
    const float* __restrict__ b_D, const float* __restrict__ b_out_w)
{
    const int tid = threadIdx.x;
    const int c = blockIdx.x >> 6;
    const int half = (blockIdx.x >> 5) & 1;
    const int b = blockIdx.x & 31;
    const int strm = c >> 1, dir = c & 1;

    const float* in_w = dir ? b_in_w   : f_in_w;
    const float* cwp  = dir ? b_conv_w : f_conv_w;
    const float* cbp  = dir ? b_conv_b : f_conv_b;
    const float* dtwp = dir ? b_dt_w   : f_dt_w;
    const float* dtbp = dir ? b_dt_b   : f_dt_b;
    const float* alog = dir ? b_A_log  : f_A_log;
    const float* Dpar = dir ? b_D      : f_D;
    const float* owp  = dir ? b_out_w  : f_out_w;
    const float* projw = strm ? pmw : paw;
    const float* projb = strm ? pmb : pab;
    const float* xin   = strm ? xmax : xavg;

    __shared__ float sseqP[516];      // 3 zeros + x(0..511) in scan order
    __shared__ float scon[32][17];    // per-dd consts
    __shared__ float sraw[64][38];    // staged records, pad 38 (even -> 8B-aligned float2)
    __shared__ float sdT[32][68];     // delta, transposed [dd][t]
    __shared__ float sxT[32][68];     // delta*xi, transposed
    __shared__ float sgT[32][68];     // g = silu(z)*wfold, transposed
    __shared__ float syT[32][68];     // scan outputs, transposed
    __shared__ float sybase[64];      // per-t Sum_dd g*D*xi

    sseqP[tid + 3] = xin[b * 512 + (dir ? (511 - tid) : tid)];
    if (tid < 3) sseqP[tid] = 0.f;
    if (tid < 32) {
        int ddz = tid, d = half * 32 + ddz;
        const float* rowx = in_w + d * 32;
        const float* rowz = in_w + (64 + d) * 32;
        float u = 0.f, v = 0.f, u2 = 0.f, v2 = 0.f, wf = 0.f;
#pragma unroll
        for (int m = 0; m < 32; ++m) {
            u  = fmaf(rowx[m], projw[m], u);
            v  = fmaf(rowx[m], projb[m], v);
            u2 = fmaf(rowz[m], projw[m], u2);
            v2 = fmaf(rowz[m], projb[m], v2);
            wf = fmaf(outw_outer[m], owp[m * 64 + d], wf);
        }
        scon[ddz][0] = cwp[d * 4 + 0];
        scon[ddz][1] = cwp[d * 4 + 1];
        scon[ddz][2] = cwp[d * 4 + 2];
        scon[ddz][3] = cwp[d * 4 + 3];
        scon[ddz][4] = cbp[d];
        scon[ddz][5] = u;  scon[ddz][6] = v;
        scon[ddz][7] = dtwp[d * 2]; scon[ddz][8] = dtwp[d * 2 + 1]; scon[ddz][9] = dtbp[d];
        scon[ddz][10] = u2; scon[ddz][11] = v2;
        scon[ddz][12] = wf; scon[ddz][13] = Dpar[d];
    }

    const int dd = tid >> 4;          // 0..31
    const int s  = tid & 15;          // 0..15
    const int d  = half * 32 + dd;
    const float cA = -expf(alog[d * 16 + s]) * 1.44269504088896340736f;
    float h = 0.f;

    const int tt8 = tid >> 3;         // 0..63 (precompute/fold row)
    const int j8  = tid & 7;
    const int cb_idx = c * 32 + b;
    const float* dbcB = dbc + (size_t)cb_idx * 512 * RECW;
    __syncthreads();

    for (int chunk = 0; chunk < 8; ++chunk) {
        const int ibase = chunk * 64;

        // stage 64 records (2304 floats, coalesced global, padded LDS rows)
        {
            const float* src = dbcB + (size_t)ibase * RECW;
            for (int i = tid; i < 64 * RECW; i += 512) {
                sraw[i / RECW][i % RECW] = src[i];
            }
        }
        __syncthreads();

        // precompute transposed per-(t,dd) quantities + sybase
        {
            const int t = ibase + tt8;
            float x0 = sseqP[t], x1 = sseqP[t + 1], x2 = sseqP[t + 2], x3 = sseqP[t + 3];
            float vv0 = (t >= 3) ? 1.f : 0.f;
            float vv1 = (t >= 2) ? 1.f : 0.f;
            float vv2 = (t >= 1) ? 1.f : 0.f;
            float dt0 = sraw[tt8][0], dt1 = sraw[tt8][1];
            float ybp = 0.f;
#pragma unroll
            for (int k = 0; k < 4; ++k) {
                int dq = j8 * 4 + k;
                float cw0 = scon[dq][0], cw1 = scon[dq][1], cw2 = scon[dq][2], cw3 = scon[dq][3];
                float cb  = scon[dq][4];
                float u = scon[dq][5], v = scon[dq][6];
                float dw0 = scon[dq][7], dw1 = scon[dq][8], dbv = scon[dq][9];
                float u2 = scon[dq][10], v2 = scon[dq][11];
                float wf = scon[dq][12], Dd = scon[dq][13];
                float xc = cw0 * fmaf(x0, u, vv0 * v)
                         + cw1 * fmaf(x1, u, vv1 * v)
                         + cw2 * fmaf(x2, u, vv2 * v)
                         + cw3 * fmaf(x3, u, v) + cb;
                float xi = xc / (1.f + __expf(-xc));
                float pre = fmaf(dt0, dw0, fmaf(dt1, dw1, dbv));
                float sp = (pre > 20.f) ? pre : log1pf(__expf(pre));
                float zv = fmaf(x3, u2, v2);
                float g = (zv / (1.f + __expf(-zv))) * wf;
                sdT[dq][tt8] = sp;
                sxT[dq][tt8] = sp * xi;
                sgT[dq][tt8] = g;
                ybp = fmaf(g * Dd, xi, ybp);
            }
            ybp += __shfl_xor(ybp, 1);
            ybp += __shfl_xor(ybp, 2);
            ybp += __shfl_xor(ybp, 4);
            if (j8 == 0) sybase[tt8] = ybp;
        }
        __syncthreads();

        // scan: 16 m-iters x 4 steps; h carried in-register across chunks
        {
            const float4* dT = reinterpret_cast<const float4*>(&sdT[dd][0]);
            const float4* xT = reinterpret_cast<const float4*>(&sxT[dd][0]);
            const float4* gT = reinterpret_cast<const float4*>(&sgT[dd][0]);
#pragma unroll 2
            for (int m = 0; m < 16; ++m) {
                float4 de = dT[m], dx = xT[m], gq = gT[m];
                float2 bc0 = *reinterpret_cast<const float2*>(&sraw[4 * m + 0][2 + 2 * s]);
                float2 bc1 = *reinterpret_cast<const float2*>(&sraw[4 * m + 1][2 + 2 * s]);
                float2 bc2 = *reinterpret_cast<const float2*>(&sraw[4 * m + 2][2 + 2 * s]);
                float2 bc3 = *reinterpret_cast<const float2*>(&sraw[4 * m + 3][2 + 2 * s]);
                float4 val;
                float a, pc;
                a = exp2f(de.x * cA); h = fmaf(a, h, dx.x * bc0.x); pc = h * bc0.y;
                pc = DPP_ADD(pc, 0x101); pc = DPP_ADD(pc, 0x102);
                pc = DPP_ADD(pc, 0x104); pc = DPP_ADD(pc, 0x108);
                val.x = pc * gq.x;
                a = exp2f(de.y * cA); h = fmaf(a, h, dx.y * bc1.x); pc = h * bc1.y;
                pc = DPP_ADD(pc, 0x101); pc = DPP_ADD(pc, 0x102);
                pc = DPP_ADD(pc, 0x104); pc = DPP_ADD(pc, 0x108);
                val.y = pc * gq.y;
                a = exp2f(de.z * cA); h = fmaf(a, h, dx.z * bc2.x); pc = h * bc2.y;
                pc = DPP_ADD(pc, 0x101); pc = DPP_ADD(pc, 0x102);
                pc = DPP_ADD(pc, 0x104); pc = DPP_ADD(pc, 0x108);
                val.z = pc * gq.z;
                a = exp2f(de.w * cA); h = fmaf(a, h, dx.w * bc3.x); pc = h * bc3.y;
                pc = DPP_ADD(pc, 0x101); pc = DPP_ADD(pc, 0x102);
                pc = DPP_ADD(pc, 0x104); pc = DPP_ADD(pc, 0x108);
                val.w = pc * gq.w;
                if (s == 0) *reinterpret_cast<float4*>(&syT[dd][4 * m]) = val;
            }
        }
        __syncthreads();

        // fold over 32 dd -> scalar partial
        {
            float acc = syT[j8 * 4][tt8] + syT[j8 * 4 + 1][tt8]
                      + syT[j8 * 4 + 2][tt8] + syT[j8 * 4 + 3][tt8];
            acc += __shfl_xor(acc, 1);
            acc += __shfl_xor(acc, 2);
            acc += __shfl_xor(acc, 4);
            if (j8 == 0) {
                int i = ibase + tt8;
                int l = dir ? (511 - i) : i;
                ypart[((c * 2 + half) * 32 + b) * 512 + l] = acc + sybase[tt8];
            }
        }
        __syncthreads();
    }
}

__global__ __launch_bounds__(256) void kfinal(const float* __restrict__ xavg,
                                              const float* __restrict__ xmax,
                                              const float* __restrict__ ypart,
                                              const float* __restrict__ gate_w,
                                              const float* __restrict__ gate_b,
                                              const float* __restrict__ out_b,
                                              float* __restrict__ out) {
    const int idx = blockIdx.x * 256 + threadIdx.x;   // 0..16383
    float xa = xavg[idx], xm = xmax[idx];
    float alpha = 1.f / (1.f + __expf(-(fmaf(xa, gate_w[0], fmaf(xm, gate_w[1], gate_b[0])))));
    float sa = ypart[0 * 16384 + idx] + ypart[1 * 16384 + idx]
             + ypart[2 * 16384 + idx] + ypart[3 * 16384 + idx];
    float sm = ypart[4 * 16384 + idx] + ypart[5 * 16384 + idx]
             + ypart[6 * 16384 + idx] + ypart[7 * 16384 + idx];
    float y = alpha * sa + (1.f - alpha) * sm + out_b[0];
    out[idx] = 1.f / (1.f + __expf(-y));
}

extern "C" void kernel_launch(void* const* d_in, const int* in_sizes, int n_in,
                              void* d_out, int out_size, void* d_ws, size_t ws_size,
                              hipStream_t stream) {
    const float* inp = (const float*)d_in[0];
    const float* paw = (const float*)d_in[1];
    const float* pab = (const float*)d_in[2];
    const float* pmw = (const float*)d_in[3];
    const float* pmb = (const float*)d_in[4];
    const float* gw  = (const float*)d_in[5];
    const float* gb  = (const float*)d_in[6];
    const float* ow  = (const float*)d_in[7];
    const float* ob  = (const float*)d_in[8];

    float* ws = (float*)d_ws;
    float* xavg = ws;
    float* xmax = ws + 16384;
    float* ypart = ws + 32768;
    float* dbc = ws + 163840;
    float* out = (float*)d_out;

    kreduce<<<16384, 256, 0, stream>>>(inp, xavg, xmax);
    kprep<<<256, 512, 0, stream>>>(
        xavg, xmax, dbc, paw, pab, pmw, pmb,
        (const float*)d_in[9],  (const float*)d_in[10], (const float*)d_in[11], (const float*)d_in[12],
        (const float*)d_in[18], (const float*)d_in[19], (const float*)d_in[20], (const float*)d_in[21]);
    kscan<<<256, 512, 0, stream>>>(
        xavg, xmax, dbc, ypart, paw, pab, pmw, pmb, ow,
        (const float*)d_in[9],  (const float*)d_in[10], (const float*)d_in[11],
        (const float*)d_in[13], (const float*)d_in[14], (const float*)d_in[15],
        (const float*)d_in[16], (const float*)d_in[17],
        (const float*)d_in[18], (const float*)d_in[19], (const float*)d_in[20],
        (const float*)d_in[22], (const float*)d_in[23], (const float*)d_in[24],
        (const float*)d_in[25], (const float*)d_in[26]);
    kfinal<<<64, 256, 0, stream>>>(xavg, xmax, ypart, gw, gb, ob, out);
}

// Round 11
// 125.912 us; speedup vs baseline: 2.3042x; 1.1189x over previous
//
#include <hip/hip_runtime.h>
#include <math.h>

// ws float-offset layout (ws >= 1 GiB, we use ~56 MB):
// xavg  [0, 16384)
// xmax  [16384, 32768)
// ypart [32768, 294912)                16 slots x 16384: slot = c*4 + dquarter
// PD    [294912, +4194304)             delta^T   [c][b][chunk][d][t]  (64x64 tiles)
// PX    PD+4194304                     delta*xi^T
// PG    PX+4194304                     g^T  (silu(z)*wfold)
// BCB   PG+4194304 (+524288)           B [c][b][chunk][s][t]
// BCC   BCB+524288                     C [c][b][chunk][s][t]
// YB    BCC+524288 (+65536)            ybase [c][b][t]
#define OFF_YPART 32768
#define OFF_PD    294912
#define OFF_PX    (OFF_PD + 4194304)
#define OFF_PG    (OFF_PX + 4194304)
#define OFF_BCB   (OFF_PG + 4194304)
#define OFF_BCC   (OFF_BCB + 524288)
#define OFF_YB    (OFF_BCC + 524288)

__global__ __launch_bounds__(256) void kreduce(const float* __restrict__ in,
                                               float* __restrict__ xavg,
                                               float* __restrict__ xmax) {
    const int bl = blockIdx.x;            // 0..16383  (= b*512 + l)
    const float* p = in + (size_t)bl * 4096;
    const int t = threadIdx.x;
    float s = 0.f, m = -INFINITY;
#pragma unroll
    for (int it = 0; it < 4; ++it) {
        float4 v = *reinterpret_cast<const float4*>(p + (size_t)(it * 256 + t) * 4);
        s += v.x + v.y + v.z + v.w;
        m = fmaxf(m, fmaxf(fmaxf(v.x, v.y), fmaxf(v.z, v.w)));
    }
#pragma unroll
    for (int o = 1; o < 64; o <<= 1) {
        s += __shfl_xor(s, o);
        m = fmaxf(m, __shfl_xor(m, o));
    }
    __shared__ float ls[4], lm[4];
    const int w = t >> 6;
    if ((t & 63) == 0) { ls[w] = s; lm[w] = m; }
    __syncthreads();
    if (t == 0) {
        s = ls[0] + ls[1] + ls[2] + ls[3];
        m = fmaxf(fmaxf(lm[0], lm[1]), fmaxf(lm[2], lm[3]));
        xavg[bl] = s * (1.f / 4096.f);
        xmax[bl] = m;
    }
}

// slot of dbc j-index (j: 0,1=dt; 2..17=B; 18..33=C) in interleaved record
__device__ __forceinline__ int dbc_slot(int j) {
    return j < 2 ? j : (j < 18 ? 2 * j - 2 : 2 * j - 33);
}

// kprep: A-phases + full A3 precompute, pre-transposed outputs.
// One block per (c, b, chunk): 4*32*8 = 1024 blocks x 512 threads (4 blocks/CU).
__global__ __launch_bounds__(512) void kprep(
    const float* __restrict__ xavg, const float* __restrict__ xmax,
    float* __restrict__ ws,
    const float* __restrict__ paw, const float* __restrict__ pab,
    const float* __restrict__ pmw, const float* __restrict__ pmb,
    const float* __restrict__ outw_outer,
    const float* __restrict__ f_in_w, const float* __restrict__ f_conv_w,
    const float* __restrict__ f_conv_b, const float* __restrict__ f_xproj_w,
    const float* __restrict__ f_dt_w, const float* __restrict__ f_dt_b,
    const float* __restrict__ f_D, const float* __restrict__ f_out_w,
    const float* __restrict__ b_in_w, const float* __restrict__ b_conv_w,
    const float* __restrict__ b_conv_b, const float* __restrict__ b_xproj_w,
    const float* __restrict__ b_dt_w, const float* __restrict__ b_dt_b,
    const float* __restrict__ b_D, const float* __restrict__ b_out_w)
{
    const int tid = threadIdx.x;
    const int c  = blockIdx.x >> 8;
    const int b  = (blockIdx.x >> 3) & 31;
    const int cq = blockIdx.x & 7;
    const int strm = c >> 1, dir = c & 1;

    const float* in_w = dir ? b_in_w   : f_in_w;
    const float* cwp  = dir ? b_conv_w : f_conv_w;
    const float* cbp  = dir ? b_conv_b : f_conv_b;
    const float* xpw  = dir ? b_xproj_w: f_xproj_w;
    const float* dtwp = dir ? b_dt_w   : f_dt_w;
    const float* dtbp = dir ? b_dt_b   : f_dt_b;
    const float* Dpar = dir ? b_D      : f_D;
    const float* owp  = dir ? b_out_w  : f_out_w;
    const float* projw = strm ? pmw : paw;
    const float* projb = strm ? pmb : pab;
    const float* xin   = strm ? xmax : xavg;

    __shared__ float sseq4[68];       // x at t = cq*64-3+i (scan order), 0 for OOB
    __shared__ float su[128], sv[128];
    __shared__ float scw[64][4], scb[64], sdtw[64][2], sdtb[64], sD[64], swf[64];
    __shared__ float sxp[34][68];
    __shared__ float sxi[64][68];
    __shared__ float sdbc[64][37];    // pad 37: conflict-free-ish strided column reads

    if (tid < 67) {
        int g = cq * 64 - 3 + tid;
        float val = 0.f;
        if (g >= 0) val = xin[b * 512 + (dir ? (511 - g) : g)];
        sseq4[tid] = val;
    }
    if (tid < 128) {
        float u = 0.f, v = 0.f;
        const float* row = in_w + tid * 32;
#pragma unroll
        for (int m = 0; m < 32; ++m) {
            u = fmaf(row[m], projw[m], u);
            v = fmaf(row[m], projb[m], v);
        }
        su[tid] = u; sv[tid] = v;
    }
    if (tid < 64) {
#pragma unroll
        for (int k = 0; k < 4; ++k) scw[tid][k] = cwp[tid * 4 + k];
        scb[tid] = cbp[tid];
        sdtw[tid][0] = dtwp[tid * 2];
        sdtw[tid][1] = dtwp[tid * 2 + 1];
        sdtb[tid] = dtbp[tid];
        sD[tid] = Dpar[tid];
        float wf = 0.f;
#pragma unroll
        for (int m = 0; m < 32; ++m) wf = fmaf(outw_outer[m], owp[m * 64 + tid], wf);
        swf[tid] = wf;
    }
    for (int i = tid; i < 34 * 64; i += 512) sxp[i >> 6][i & 63] = xpw[i];
    __syncthreads();

    const int ll8 = tid >> 3;  // 0..63 (t within chunk)
    const int j8  = tid & 7;
    const int gi  = cq * 64 + ll8;   // global t (scan order)

    // A1: xi for all 64 d
    {
        float t0 = sseq4[ll8], t1 = sseq4[ll8 + 1], t2 = sseq4[ll8 + 2], t3 = sseq4[ll8 + 3];
        float vv0 = (gi >= 3) ? 1.f : 0.f;
        float vv1 = (gi >= 2) ? 1.f : 0.f;
        float vv2 = (gi >= 1) ? 1.f : 0.f;
#pragma unroll
        for (int k = 0; k < 8; ++k) {
            int di = j8 * 8 + k;
            float u = su[di], v = sv[di];
            float xc = scw[di][0] * fmaf(t0, u, vv0 * v)
                     + scw[di][1] * fmaf(t1, u, vv1 * v)
                     + scw[di][2] * fmaf(t2, u, vv2 * v)
                     + scw[di][3] * fmaf(t3, u, v);
            xc += scb[di];
            float sig = 1.f / (1.f + __expf(-xc));
            sxi[ll8][di] = xc * sig;
        }
    }
    __syncthreads();

    // A2: dbc = xi @ xproj_w.T -> LDS records (interleaved layout).
    // unroll 2 only: full unroll spills past the VGPR budget (rounds 2-8 lesson).
    {
        float a0 = 0.f, a1 = 0.f, a2 = 0.f, a3 = 0.f, a4 = 0.f;
        const float4* xr4 = reinterpret_cast<const float4*>(&sxi[ll8][0]);
        const float4* r0 = reinterpret_cast<const float4*>(&sxp[j8 + 0][0]);
        const float4* r1 = reinterpret_cast<const float4*>(&sxp[j8 + 8][0]);
        const float4* r2 = reinterpret_cast<const float4*>(&sxp[j8 + 16][0]);
        const float4* r3 = reinterpret_cast<const float4*>(&sxp[j8 + 24][0]);
        const float4* r4 = (j8 < 2) ? reinterpret_cast<const float4*>(&sxp[j8 + 32][0]) : r0;
        bool extra = (j8 < 2);
#pragma unroll 2
        for (int q = 0; q < 16; ++q) {
            float4 x = xr4[q];
            float4 w;
            w = r0[q]; a0 = fmaf(x.x,w.x,fmaf(x.y,w.y,fmaf(x.z,w.z,fmaf(x.w,w.w,a0))));
            w = r1[q]; a1 = fmaf(x.x,w.x,fmaf(x.y,w.y,fmaf(x.z,w.z,fmaf(x.w,w.w,a1))));
            w = r2[q]; a2 = fmaf(x.x,w.x,fmaf(x.y,w.y,fmaf(x.z,w.z,fmaf(x.w,w.w,a2))));
            w = r3[q]; a3 = fmaf(x.x,w.x,fmaf(x.y,w.y,fmaf(x.z,w.z,fmaf(x.w,w.w,a3))));
            if (extra) { w = r4[q]; a4 = fmaf(x.x,w.x,fmaf(x.y,w.y,fmaf(x.z,w.z,fmaf(x.w,w.w,a4)))); }
        }
        sdbc[ll8][dbc_slot(j8)]      = a0;
        sdbc[ll8][dbc_slot(j8 + 8)]  = a1;
        sdbc[ll8][dbc_slot(j8 + 16)] = a2;
        sdbc[ll8][dbc_slot(j8 + 24)] = a3;
        if (extra) sdbc[ll8][dbc_slot(j8 + 32)] = a4;
    }
    __syncthreads();

    // A3: delta (softplus), delta*xi, g = silu(z)*wfold, ybase -> global transposed
    {
        const size_t tile = ((size_t)(c * 32 + b) * 8 + cq) * 4096;
        float dt0 = sdbc[ll8][0], dt1 = sdbc[ll8][1];
        float x3 = sseq4[ll8 + 3];   // = x[gi]
        float ybp = 0.f;
#pragma unroll 2
        for (int k = 0; k < 8; ++k) {
            int di = j8 * 8 + k;
            float xi = sxi[ll8][di];
            float pre = fmaf(dt0, sdtw[di][0], fmaf(dt1, sdtw[di][1], sdtb[di]));
            float sp = (pre > 20.f) ? pre : __logf(1.f + __expf(pre));
            float zv = fmaf(x3, su[64 + di], sv[64 + di]);
            float g = (zv / (1.f + __expf(-zv))) * swf[di];
            ws[OFF_PD + tile + di * 64 + ll8] = sp;
            ws[OFF_PX + tile + di * 64 + ll8] = sp * xi;
            ws[OFF_PG + tile + di * 64 + ll8] = g;
            ybp = fmaf(g * sD[di], xi, ybp);
        }
        ybp += __shfl_xor(ybp, 1);
        ybp += __shfl_xor(ybp, 2);
        ybp += __shfl_xor(ybp, 4);
        if (j8 == 0) ws[OFF_YB + (size_t)(c * 32 + b) * 512 + gi] = ybp;
    }

    // B/C copy -> [s][t] layout (coalesced over t)
    {
        const size_t bb = ((size_t)(c * 32 + b) * 8 + cq) * 1024;
        for (int i = tid; i < 1024; i += 512) {
            int s = i >> 6, t = i & 63;
            ws[OFF_BCB + bb + i] = sdbc[t][2 + 2 * s];
            ws[OFF_BCC + bb + i] = sdbc[t][3 + 2 * s];
        }
    }
}

// DPP add over 16-lane rows: after shl 1,2,4,8, lane (s==0) holds the row sum.
#define DPP_ADD(v, ctrl) ((v) + __int_as_float(__builtin_amdgcn_update_dpp(0, __float_as_int(v), (ctrl), 0xF, 0xF, true)))

// kscan: pure scan. One block per (c, dquarter, b): 4*4*32 = 512 blocks x 256 threads.
__global__ __launch_bounds__(256) void kscan(
    float* __restrict__ ws,
    const float* __restrict__ f_A_log, const float* __restrict__ b_A_log)
{
    const int tid = threadIdx.x;
    const int c  = blockIdx.x >> 7;
    const int dq = (blockIdx.x >> 5) & 3;
    const int b  = blockIdx.x & 31;
    const int dir = c & 1;
    const float* alog = dir ? b_A_log : f_A_log;

    const int dd = tid >> 4;          // 0..15 (local d in quarter)
    const int s  = tid & 15;
    const int d  = dq * 16 + dd;      // global d 0..63
    const float cA = -expf(alog[d * 16 + s]) * 1.44269504088896340736f;
    float h = 0.f;

    __shared__ float sd[16][68], sx[16][68], sg[16][68];
    __shared__ float sB[16][68], sC[16][68];
    __shared__ float syT[16][68];
    __shared__ float syb[64];

    // staging map: 256 thr = 16 rows x 16 col-quads
    const int srow = tid >> 4;
    const int scol = (tid & 15) * 4;
    float* ypart = ws + OFF_YPART;

    for (int chunk = 0; chunk < 8; ++chunk) {
        const size_t tb = (size_t)(c * 32 + b) * 8 + chunk;
        const float* pd = ws + OFF_PD + tb * 4096 + dq * 1024;
        const float* px = ws + OFF_PX + tb * 4096 + dq * 1024;
        const float* pg = ws + OFF_PG + tb * 4096 + dq * 1024;
        const float* pB = ws + OFF_BCB + tb * 1024;
        const float* pC = ws + OFF_BCC + tb * 1024;

        // stage (straight coalesced copies; layouts already match)
        *reinterpret_cast<float4*>(&sd[srow][scol]) =
            *reinterpret_cast<const float4*>(pd + srow * 64 + scol);
        *reinterpret_cast<float4*>(&sx[srow][scol]) =
            *reinterpret_cast<const float4*>(px + srow * 64 + scol);
        *reinterpret_cast<float4*>(&sg[srow][scol]) =
            *reinterpret_cast<const float4*>(pg + srow * 64 + scol);
        *reinterpret_cast<float4*>(&sB[srow][scol]) =
            *reinterpret_cast<const float4*>(pB + srow * 64 + scol);
        *reinterpret_cast<float4*>(&sC[srow][scol]) =
            *reinterpret_cast<const float4*>(pC + srow * 64 + scol);
        if (dq == 0 && tid < 64) syb[tid] = ws[OFF_YB + (size_t)(c * 32 + b) * 512 + chunk * 64 + tid];
        __syncthreads();

        // scan 16 m-iters x 4 steps; h carried across chunks
        {
#pragma unroll 2
            for (int m = 0; m < 16; ++m) {
                float4 de = *reinterpret_cast<const float4*>(&sd[dd][4 * m]);
                float4 dx = *reinterpret_cast<const float4*>(&sx[dd][4 * m]);
                float4 gq = *reinterpret_cast<const float4*>(&sg[dd][4 * m]);
                float4 Bq = *reinterpret_cast<const float4*>(&sB[s][4 * m]);
                float4 Cq = *reinterpret_cast<const float4*>(&sC[s][4 * m]);
                float4 val;
                float a, pc;
                a = exp2f(de.x * cA); h = fmaf(a, h, dx.x * Bq.x); pc = h * Cq.x;
                pc = DPP_ADD(pc, 0x101); pc = DPP_ADD(pc, 0x102);
                pc = DPP_ADD(pc, 0x104); pc = DPP_ADD(pc, 0x108);
                val.x = pc * gq.x;
                a = exp2f(de.y * cA); h = fmaf(a, h, dx.y * Bq.y); pc = h * Cq.y;
                pc = DPP_ADD(pc, 0x101); pc = DPP_ADD(pc, 0x102);
                pc = DPP_ADD(pc, 0x104); pc = DPP_ADD(pc, 0x108);
                val.y = pc * gq.y;
                a = exp2f(de.z * cA); h = fmaf(a, h, dx.z * Bq.z); pc = h * Cq.z;
                pc = DPP_ADD(pc, 0x101); pc = DPP_ADD(pc, 0x102);
                pc = DPP_ADD(pc, 0x104); pc = DPP_ADD(pc, 0x108);
                val.z = pc * gq.z;
                a = exp2f(de.w * cA); h = fmaf(a, h, dx.w * Bq.w); pc = h * Cq.w;
                pc = DPP_ADD(pc, 0x101); pc = DPP_ADD(pc, 0x102);
                pc = DPP_ADD(pc, 0x104); pc = DPP_ADD(pc, 0x108);
                val.w = pc * gq.w;
                if (s == 0) *reinterpret_cast<float4*>(&syT[dd][4 * m]) = val;
            }
        }
        __syncthreads();

        // fold over 16 dd -> scalar partial into slot (c*4 + dq)
        {
            const int tt4 = tid >> 2;   // 0..63
            const int j4  = tid & 3;
            float acc = syT[j4 * 4][tt4] + syT[j4 * 4 + 1][tt4]
                      + syT[j4 * 4 + 2][tt4] + syT[j4 * 4 + 3][tt4];
            acc += __shfl_xor(acc, 1);
            acc += __shfl_xor(acc, 2);
            if (j4 == 0) {
                int i = chunk * 64 + tt4;
                int l = dir ? (511 - i) : i;
                float res = acc + (dq == 0 ? syb[tt4] : 0.f);
                ypart[((c * 4 + dq) * 32 + b) * 512 + l] = res;
            }
        }
        __syncthreads();
    }
}

__global__ __launch_bounds__(256) void kfinal(const float* __restrict__ xavg,
                                              const float* __restrict__ xmax,
                                              const float* __restrict__ ypart,
                                              const float* __restrict__ gate_w,
                                              const float* __restrict__ gate_b,
                                              const float* __restrict__ out_b,
                                              float* __restrict__ out) {
    const int idx = blockIdx.x * 256 + threadIdx.x;   // 0..16383
    float xa = xavg[idx], xm = xmax[idx];
    float alpha = 1.f / (1.f + __expf(-(fmaf(xa, gate_w[0], fmaf(xm, gate_w[1], gate_b[0])))));
    float sa = 0.f, sm = 0.f;
#pragma unroll
    for (int k = 0; k < 8; ++k)  sa += ypart[k * 16384 + idx];
#pragma unroll
    for (int k = 8; k < 16; ++k) sm += ypart[k * 16384 + idx];
    float y = alpha * sa + (1.f - alpha) * sm + out_b[0];
    out[idx] = 1.f / (1.f + __expf(-y));
}

extern "C" void kernel_launch(void* const* d_in, const int* in_sizes, int n_in,
                              void* d_out, int out_size, void* d_ws, size_t ws_size,
                              hipStream_t stream) {
    const float* inp = (const float*)d_in[0];
    const float* paw = (const float*)d_in[1];
    const float* pab = (const float*)d_in[2];
    const float* pmw = (const float*)d_in[3];
    const float* pmb = (const float*)d_in[4];
    const float* gw  = (const float*)d_in[5];
    const float* gb  = (const float*)d_in[6];
    const float* ow  = (const float*)d_in[7];
    const float* ob  = (const float*)d_in[8];

    float* ws = (float*)d_ws;
    float* xavg = ws;
    float* xmax = ws + 16384;
    float* ypart = ws + OFF_YPART;
    float* out = (float*)d_out;

    kreduce<<<16384, 256, 0, stream>>>(inp, xavg, xmax);
    kprep<<<1024, 512, 0, stream>>>(
        xavg, xmax, ws, paw, pab, pmw, pmb, ow,
        (const float*)d_in[9],  (const float*)d_in[10], (const float*)d_in[11], (const float*)d_in[12],
        (const float*)d_in[13], (const float*)d_in[14], (const float*)d_in[16], (const float*)d_in[17],
        (const float*)d_in[18], (const float*)d_in[19], (const float*)d_in[20], (const float*)d_in[21],
        (const float*)d_in[22], (const float*)d_in[23], (const float*)d_in[25], (const float*)d_in[26]);
    kscan<<<512, 256, 0, stream>>>(
        ws, (const float*)d_in[15], (const float*)d_in[24]);
    kfinal<<<64, 256, 0, stream>>>(xavg, xmax, ypart, gw, gb, ob, out);
}